// Round 13
// baseline (88.203 us; speedup 1.0000x reference)
//
#include <hip/hip_runtime.h>
#include <hip/hip_bf16.h>
#include <cstdint>

// STFT via radix-2 split GEMM (R11 math, R12 dataflow).
//   E[f] from even samples (A2 even-col gather), O~[f] from odd samples with
//   twiddle folded; C[f] = E+O~, C[512-f] = conj(E-O~), f=0..255.
// R12 dataflow: B = 64-frame per-parity signal windows RESIDENT in LDS (staged
// once per block via global_load_lds, 2x17KB); A2 (1 MB, L2-resident) is read
// global->VGPR per fragment -- NO DMA, NO K-loop barriers. 256-thr blocks,
// 34 KB LDS, launch_bounds(256,4) -> 4 blocks/CU, grid 1024 = 4/CU exactly.

#define HOP 256
#define FB 513
#define NT 1025
#define NBATCH 16
#define SIGLEN 262144
#define HSIG 131584          // half-rate padded length (SIGP/2)
#define NKT 16               // K tiles: 512 (per parity) / 32
#define PW 17408             // parity window stride in LDS (17152 used + pad)
#define WUSED 17152          // (63*128 + 512) * 2 bytes per parity

typedef __attribute__((ext_vector_type(8))) short short8;
typedef __attribute__((ext_vector_type(4))) float f32x4;
typedef unsigned int u32;

__device__ __forceinline__ unsigned short f2bf(float f) {
  u32 u = __float_as_uint(f);
  u = (u + 0x7FFFu + ((u >> 16) & 1u)) >> 16;   // RNE
  return (unsigned short)u;
}

// ---- fused prologue (verified R11) ----
// blocks [0,256):  A2[r][j] (1024x512): r -> sg=r>>5, h=(r>>4)&1 (parity),
//   p=(r>>1)&7, ri=r&1, f=sg*8+p;  A2[r][j] = kern[ri*513+f][2j+h]
// blocks [256,1284): Se[b][m]=bf16(xpad[2m]), So[b][m]=bf16(xpad[2m+1])
#define NA2_BLK 256
#define NS2_BLK 1028
__global__ __launch_bounds__(256) void prep_all(const float* __restrict__ kern,
                                                const float* __restrict__ sig,
                                                unsigned short* __restrict__ A2,
                                                unsigned short* __restrict__ Se,
                                                unsigned short* __restrict__ So) {
  if (blockIdx.x < NA2_BLK) {
    size_t i8 = ((size_t)blockIdx.x * 256 + threadIdx.x) * 8;
    int r = (int)(i8 >> 9);
    int j0 = (int)(i8 & 511);
    int sg = r >> 5, h = (r >> 4) & 1, p = (r >> 1) & 7, ri = r & 1;
    int f = sg * 8 + p;
    const float* s = kern + ((size_t)(ri * FB + f) << 10) + 2 * j0 + h;
    short8 v;
#pragma unroll
    for (int e = 0; e < 8; ++e) v[e] = (short)f2bf(s[2 * e]);
    *(short8*)(A2 + i8) = v;
  } else {
    size_t i8 = ((size_t)(blockIdx.x - NA2_BLK) * 256 + threadIdx.x) * 8;
    int b = (int)(i8 / HSIG);
    int m0 = (int)(i8 - (size_t)b * HSIG);
    const float* sb = sig + (size_t)b * SIGLEN;
    short8 ve, vo;
#pragma unroll
    for (int e = 0; e < 8; ++e) {
      int m = m0 + e;
      int je = 2 * m - 512;
      je = (je < 0) ? -je : je;
      je = (je >= SIGLEN) ? (2 * SIGLEN - 2 - je) : je;
      int jo = 2 * m - 511;
      jo = (jo < 0) ? -jo : jo;
      jo = (jo >= SIGLEN) ? (2 * SIGLEN - 2 - jo) : jo;
      ve[e] = (short)f2bf(sb[je]);
      vo[e] = (short)f2bf(sb[jo]);
    }
    *(short8*)(Se + (size_t)b * HSIG + m0) = ve;
    *(short8*)(So + (size_t)b * HSIG + m0) = vo;
  }
}

// async 16B global->LDS. LDS dest is wave-uniform; HW adds lane*16.
__device__ __forceinline__ void async16(void* lds, const void* g) {
  __builtin_amdgcn_global_load_lds(
      (const __attribute__((address_space(1))) u32*)g,
      (__attribute__((address_space(3))) u32*)lds, 16, 0, 0);
}

// ---- main kernel ----
// 256 thr = 4 waves; block tile = 256 A-rows x 64 frames; wave = 64 rows (wid).
// Window swizzle (both sides): p = q ^ (((q>>8)&7)<<4)  (involution; spreads
// frame rows (stride 256B) across 8 16B slots -> ~2-way conflicts = free).
__global__ __launch_bounds__(256, 4) void stft_mm(const unsigned short* __restrict__ A2,
                                                  const unsigned short* __restrict__ Se,
                                                  const unsigned short* __restrict__ So,
                                                  float* __restrict__ out) {
  __shared__ __align__(16) char sW[2 * PW];   // [even | odd] windows, 34 KB

  const int tid = threadIdx.x;
  const int lane = tid & 63;
  const int wid = tid >> 6;      // 0..3  (64-row slice of the 256-row panel)
  const int lr = lane & 15;
  const int g16 = lane >> 4;

  // bijective XCD-chunk swizzle: nwg = 1024 = 8 * 128
  const int bid = blockIdx.x;
  const int wg = (bid & 7) * 128 + (bid >> 3);
  const int mt = wg & 3;         // fastest: consecutive wg share the B window
  const int r2 = wg >> 2;
  const int nt = r2 & 15;
  const int b  = r2 >> 4;

  const int c0 = mt * 256;       // A2 row base (0..768)
  const int t0 = nt * 64;        // frame base  (0..960)

  // ---- stage both parity windows once (DMA), then no barriers ever ----
  const char* SeB = (const char*)Se + ((size_t)b * HSIG + (size_t)t0 * 128) * 2;
  const char* SoB = (const char*)So + ((size_t)b * HSIG + (size_t)t0 * 128) * 2;
#pragma unroll
  for (int i = 0; i < 9; ++i) {
    const int c = i * 4 + wid;               // chunk 0..35 (64 granules each)
    if (c < 34) {
      const int par = (c >= 17);
      const int lc = c - par * 17;
      u32 P = (u32)(lc * 64 + lane) * 16u;   // physical byte within parity win
      u32 q = P ^ (((P >> 8) & 7u) << 4);    // logical byte (involution)
      if (q > WUSED - 16) q = WUSED - 16;    // clamp pad granules (dup, unused)
      async16(sW + par * PW + (size_t)lc * 1024u, (par ? SoB : SeB) + q);
    }
  }
  asm volatile("s_waitcnt vmcnt(0)" ::: "memory");
  __syncthreads();

  // per-lane bases
  const char* pA = (const char*)A2 + (((size_t)(c0 + wid * 64 + lr)) << 10) + g16 * 16;
  u32 qB[4];
#pragma unroll
  for (int ni = 0; ni < 4; ++ni) qB[ni] = (u32)((ni * 16 + lr) * 256 + g16 * 16);

  f32x4 acc[4][4] = {};

#pragma unroll
  for (int kt = 0; kt < NKT; ++kt) {
    // A fragments: global->VGPR (L2-resident; 4 waves/SIMD hide latency)
    short8 af0 = *(const short8*)(pA + 0 * 16384 + kt * 64);
    short8 af1 = *(const short8*)(pA + 1 * 16384 + kt * 64);
    short8 af2 = *(const short8*)(pA + 2 * 16384 + kt * 64);
    short8 af3 = *(const short8*)(pA + 3 * 16384 + kt * 64);
#pragma unroll
    for (int ni = 0; ni < 4; ++ni) {
      u32 q = qB[ni] + (u32)(kt * 64);
      u32 p = q ^ (((q >> 8) & 7u) << 4);
      short8 be = *(const short8*)(sW + p);
      short8 bo = *(const short8*)(sW + PW + p);
      acc[0][ni] = __builtin_amdgcn_mfma_f32_16x16x32_bf16(af0, be, acc[0][ni], 0, 0, 0);
      acc[1][ni] = __builtin_amdgcn_mfma_f32_16x16x32_bf16(af1, bo, acc[1][ni], 0, 0, 0);
      acc[2][ni] = __builtin_amdgcn_mfma_f32_16x16x32_bf16(af2, be, acc[2][ni], 0, 0, 0);
      acc[3][ni] = __builtin_amdgcn_mfma_f32_16x16x32_bf16(af3, bo, acc[3][ni], 0, 0, 0);
    }
  }

  // ---- butterfly epilogue (verified R11) ----
  // E = acc[2mp], O~ = acc[2mp+1]; rowb = E row; f = (rowb>>5)*8 + ((rowb>>1)&7)
  // out[f] = (Ere+Ore, Eim+Oim);  out[512-f] = (Ere-Ore, Oim-Eim)
#pragma unroll
  for (int mp = 0; mp < 2; ++mp) {
    const int rowb = c0 + wid * 64 + mp * 32 + g16 * 4;
    const int F0 = ((rowb >> 5) << 3) + ((rowb >> 1) & 7);
#pragma unroll
    for (int ni = 0; ni < 4; ++ni) {
      const int t = t0 + ni * 16 + lr;                 // < 1024
      const f32x4 E = acc[2 * mp][ni];
      const f32x4 O = acc[2 * mp + 1][ni];
#pragma unroll
      for (int h = 0; h < 2; ++h) {
        const int f = F0 + h;
        const float Ere = E[2 * h], Eim = E[2 * h + 1];
        const float Ore = O[2 * h], Oim = O[2 * h + 1];
        *(float2*)(out + ((((size_t)b * FB + f) * NT + t) << 1)) =
            make_float2(Ere + Ore, Eim + Oim);
        *(float2*)(out + ((((size_t)b * FB + (512 - f)) * NT + t) << 1)) =
            make_float2(Ere - Ore, Oim - Eim);
      }
    }
  }
}

// ---- edge kernel (f32 direct, verified R11): f=256 all t, and t=1024 all f ----
__global__ __launch_bounds__(256) void stft_edge(const float* __restrict__ kern,
                                                 const float* __restrict__ sig,
                                                 float* __restrict__ out) {
  const int wv = blockIdx.x * 4 + (threadIdx.x >> 6);
  const int lane = threadIdx.x & 63;
  int b, f, t;
  if (wv < NBATCH * NT) {
    b = wv / NT; t = wv - b * NT; f = 256;
  } else {
    int u = wv - NBATCH * NT;
    b = u / FB; f = u - b * FB; t = NT - 1;
  }
  const float* r0 = kern + ((size_t)f << 10);
  const float* r1 = kern + ((size_t)(FB + f) << 10);
  const float* sb = sig + (size_t)b * SIGLEN;
  const int base = t * HOP - 512;
  float d0 = 0.f, d1 = 0.f;
  if (t >= 2 && t <= 1022) {
    const float4* x4 = (const float4*)(sb + base + lane * 16);
    const float4* a4 = (const float4*)(r0 + lane * 16);
    const float4* b4 = (const float4*)(r1 + lane * 16);
#pragma unroll
    for (int q = 0; q < 4; ++q) {
      float4 x = x4[q], a = a4[q], c = b4[q];
      d0 += a.x * x.x + a.y * x.y + a.z * x.z + a.w * x.w;
      d1 += c.x * x.x + c.y * x.y + c.z * x.z + c.w * x.w;
    }
  } else {
#pragma unroll 4
    for (int e = 0; e < 16; ++e) {
      int n = lane * 16 + e;
      int j = base + n;
      j = (j < 0) ? -j : j;
      j = (j >= SIGLEN) ? (2 * SIGLEN - 2 - j) : j;
      float x = sb[j];
      d0 += r0[n] * x;
      d1 += r1[n] * x;
    }
  }
#pragma unroll
  for (int m = 32; m; m >>= 1) {
    d0 += __shfl_xor(d0, m);
    d1 += __shfl_xor(d1, m);
  }
  if (lane == 0)
    *(float2*)(out + ((((size_t)b * FB + f) * NT + t) << 1)) = make_float2(d0, d1);
}

extern "C" void kernel_launch(void* const* d_in, const int* in_sizes, int n_in,
                              void* d_out, int out_size, void* d_ws, size_t ws_size,
                              hipStream_t stream) {
  const float* sig = (const float*)d_in[0];    // (16, 262144) f32
  const float* kern = (const float*)d_in[1];   // (1026, 1024) f32
  float* out = (float*)d_out;                  // (16, 513, 1025, 2) f32

  unsigned short* wsA2 = (unsigned short*)d_ws;            // 1024*512   bf16
  unsigned short* wsSe = wsA2 + (size_t)1024 * 512;        // 16*131584  bf16
  unsigned short* wsSo = wsSe + (size_t)NBATCH * HSIG;     // 16*131584  bf16
  // ws use: (524288 + 2*2105344)*2 = 9,469,952 bytes

  prep_all<<<dim3(NA2_BLK + NS2_BLK), 256, 0, stream>>>(kern, sig, wsA2, wsSe, wsSo);
  stft_mm<<<dim3(4 * 16 * NBATCH), 256, 0, stream>>>(wsA2, wsSe, wsSo, out);
  // edge waves: 16*1025 + 16*513 = 24608 = 6152 blocks * 4 waves (exact)
  stft_edge<<<dim3((NBATCH * NT + NBATCH * FB) / 4), 256, 0, stream>>>(kern, sig, out);
}

// Round 14
// 80.834 us; speedup vs baseline: 1.0912x; 1.0912x over previous
//
#include <hip/hip_runtime.h>
#include <hip/hip_bf16.h>
#include <cstdint>

// STFT as im2col GEMM:  C[b,c,t] = sum_n K[c,n] * xpad[b, t*HOP+n]
// R13 = R5 package verbatim (best verified: main 48.6us) + ONE variable:
// nontemporal epilogue stores (tests the ~1.5 TB/s strided-write-floor theory).
// Main GEMM covers channels 0..1023 x frames 0..1023; Nyquist pair
// (rows 1024,1025) and last frame (t=1024) go to stft_edge (bf16 ws, cheap).
// K-loop: 3-slot LDS ring (A 32KB + B 16KB per slot), stage-2-ahead via
// global_load_lds, counted s_waitcnt vmcnt(6), ONE raw s_barrier per K-tile.

#define HOP 256
#define NFFT 1024
#define FB 513
#define NT 1025
#define NBATCH 16
#define MCH 1026
#define MP2 1280         // padded channel rows in workspace A
#define SIGLEN 262144
#define SIGP 263168      // reflect-padded length
#define BM 256
#define BN 128
#define BK 64
#define NKT 16           // K tiles (1024 / 64)
#define SLOT_BYTES 49152 // A tile 32KB + B tile 16KB
#define LDS_BYTES (3 * SLOT_BYTES)

typedef __attribute__((ext_vector_type(8))) short short8;
typedef __attribute__((ext_vector_type(4))) float f32x4;
typedef __attribute__((ext_vector_type(2))) float f32x2;
typedef unsigned int u32;

__device__ __forceinline__ unsigned short f2bf(float f) {
  u32 u = __float_as_uint(f);
  u = (u + 0x7FFFu + ((u >> 16) & 1u)) >> 16;   // RNE
  return (unsigned short)u;
}
__device__ __forceinline__ float bf2f(unsigned short s) {
  return __uint_as_float(((u32)s) << 16);
}

// ---- prologue 1: DFT kernel f32[1026][1024] -> bf16[1280][1024], PAIR-INTERLEAVED:
//      A'[2f+ri][n] = kern[ri*513+f][n];  rows >= 1026 zero.
__global__ __launch_bounds__(256) void prep_A(const float* __restrict__ kern,
                                              unsigned short* __restrict__ A) {
  size_t i8 = ((size_t)blockIdx.x * 256 + threadIdx.x) * 8;
  int row = (int)(i8 >> 10);
  int col = (int)(i8 & 1023);
  short8 v = {0, 0, 0, 0, 0, 0, 0, 0};
  if (row < MCH) {
    int f = row >> 1, ri = row & 1;
    int src_row = ri * FB + f;
    const float* s = kern + ((size_t)src_row << 10) + col;
#pragma unroll
    for (int e = 0; e < 8; ++e) v[e] = (short)f2bf(s[e]);
  }
  *(short8*)(A + i8) = v;
}

// ---- prologue 2: reflect-pad signal f32[16][262144] -> bf16[16][263168]
__global__ __launch_bounds__(256) void prep_S(const float* __restrict__ sig,
                                              unsigned short* __restrict__ S) {
  size_t i8 = ((size_t)blockIdx.x * 256 + threadIdx.x) * 8;
  int b = (int)(i8 / SIGP);
  int i = (int)(i8 - (size_t)b * SIGP);
  const float* sb = sig + (size_t)b * SIGLEN;
  short8 v;
#pragma unroll
  for (int e = 0; e < 8; ++e) {
    int j = i + e - 512;
    j = (j < 0) ? -j : j;
    j = (j >= SIGLEN) ? (2 * SIGLEN - 2 - j) : j;
    v[e] = (short)f2bf(sb[j]);
  }
  *(short8*)(S + i8) = v;
}

// async 16B global->LDS. LDS dest is wave-uniform; HW adds lane*16.
__device__ __forceinline__ void async16(void* lds, const void* g) {
  __builtin_amdgcn_global_load_lds(
      (const __attribute__((address_space(1))) u32*)g,
      (__attribute__((address_space(3))) u32*)lds, 16, 0, 0);
}

// ---- main GEMM ----
// 512 thr = 8 waves (wr=wid>>1 in 0..3 over M, wc=wid&1 over N).
// Tiles [rows][128B] bf16 in LDS with XOR swizzle p = q ^ (((q>>7)&7)<<4)
// (R1-proven: 0 bank conflicts). Linear gload_lds dest + inverse-swizzled src.
__global__ __launch_bounds__(512, 2) void stft_mm(const unsigned short* __restrict__ A,
                                                  const unsigned short* __restrict__ S,
                                                  float* __restrict__ out) {
  extern __shared__ char smem[];

  const int tid = threadIdx.x;
  const int lane = tid & 63;
  const int wid = tid >> 6;
  const int wr = wid >> 1;   // 0..3  (M quarter)
  const int wc = wid & 1;    // 0..1  (N half)
  const int lr = lane & 15;
  const int g16 = lane >> 4;

  // bijective XCD-chunk swizzle: nwg = 512 = 8 * 64
  const int bid = blockIdx.x;
  const int wg = (bid & 7) * 64 + (bid >> 3);
  const int mt = wg & 3;
  const int r2 = wg >> 2;
  const int nt = r2 & 7;
  const int b  = r2 >> 3;

  const int c0 = mt * BM;    // 0..768 (+255 <= 1023: always valid)
  const int t0 = nt * BN;    // 0..896 (+127 <= 1023: always valid)

  const char* Ab = (const char*)A;
  const char* Sb = (const char*)(S + (size_t)b * SIGP);

  // Stage K-tile kt into ring slot s. A: 2048 granules (4/thread); B: 1024 (2/thread).
#define STAGE_TILE(kt, s)                                                      \
  {                                                                            \
    char* As_ = smem + (s) * SLOT_BYTES;                                       \
    char* Bs_ = As_ + 32768;                                                   \
    _Pragma("unroll") for (int j = 0; j < 4; ++j) {                            \
      const int G0 = j * 512 + wid * 64;                                       \
      u32 p = (u32)(G0 + lane) * 16u;                                          \
      u32 q = p ^ (((p >> 7) & 7u) << 4);                                      \
      const char* src = Ab + ((size_t)(c0 + (int)(q >> 7)) << 11)              \
                           + (kt) * 128 + (int)(q & 127u);                     \
      async16(As_ + (size_t)G0 * 16u, src);                                    \
    }                                                                          \
    _Pragma("unroll") for (int j = 0; j < 2; ++j) {                            \
      const int G0 = j * 512 + wid * 64;                                       \
      u32 p = (u32)(G0 + lane) * 16u;                                          \
      u32 q = p ^ (((p >> 7) & 7u) << 4);                                      \
      const char* src = Sb + ((size_t)(t0 + (int)(q >> 7)) << 9)               \
                           + (kt) * 128 + (int)(q & 127u);                     \
      async16(Bs_ + (size_t)G0 * 16u, src);                                    \
    }                                                                          \
  }

  // prologue: fill slots 0,1 (12 loads/thread); gate tile0 landed (leave tile1)
  STAGE_TILE(0, 0)
  STAGE_TILE(1, 1)
  asm volatile("s_waitcnt vmcnt(6)" ::: "memory");
  __builtin_amdgcn_s_barrier();
  asm volatile("" ::: "memory");

  // per-lane logical read offsets (within tile)
  u32 qa[4], qb[4];
#pragma unroll
  for (int mi = 0; mi < 4; ++mi) qa[mi] = (u32)((wr * 64 + mi * 16 + lr) * 128 + g16 * 16);
#pragma unroll
  for (int ni = 0; ni < 4; ++ni) qb[ni] = (u32)((wc * 64 + ni * 16 + lr) * 128 + g16 * 16);

  f32x4 acc[4][4] = {};

#pragma unroll
  for (int k = 0; k < NKT; ++k) {
    const char* As = smem + (k % 3) * SLOT_BYTES;
    const char* Bs = As + 32768;
    // ds-reads of tile k (valid: gated at end of k-1, visible via barrier)
    short8 af[2][4], bfv[2][4];
#pragma unroll
    for (int h = 0; h < 2; ++h) {
#pragma unroll
      for (int mi = 0; mi < 4; ++mi) {
        u32 q = qa[mi] + (u32)(h * 64);
        u32 p = q ^ (((q >> 7) & 7u) << 4);
        af[h][mi] = *(const short8*)(As + p);
      }
#pragma unroll
      for (int ni = 0; ni < 4; ++ni) {
        u32 q = qb[ni] + (u32)(h * 64);
        u32 p = q ^ (((q >> 7) & 7u) << 4);
        bfv[h][ni] = *(const short8*)(Bs + p);
      }
    }
    // stage tile k+2 into slot (k+2)%3 == (k-1)%3: its last reader finished
    // before barrier k-1  -> WAR-safe for every wave.
    if (k + 2 < NKT) STAGE_TILE(k + 2, (k + 2) % 3)
    // 32 MFMA while staging loads fly
#pragma unroll
    for (int h = 0; h < 2; ++h)
#pragma unroll
      for (int mi = 0; mi < 4; ++mi)
#pragma unroll
        for (int ni = 0; ni < 4; ++ni)
          acc[mi][ni] = __builtin_amdgcn_mfma_f32_16x16x32_bf16(
              af[h][mi], bfv[h][ni], acc[mi][ni], 0, 0, 0);
    // gate: tile k+1 landed (leave tile k+2's 6 loads in flight); then barrier
    if (k <= NKT - 3)      asm volatile("s_waitcnt vmcnt(6)" ::: "memory");
    else                   asm volatile("s_waitcnt vmcnt(0)" ::: "memory");
    __builtin_amdgcn_s_barrier();
    asm volatile("" ::: "memory");
  }
#undef STAGE_TILE

  // epilogue: D row (lane>>4)*4+r = c' (paired), col lane&15 = t.
  // R13 variable: NONTEMPORAL float2 stores (MUBUF nt) -- write-floor probe.
#pragma unroll
  for (int mi = 0; mi < 4; ++mi) {
    const int cb = c0 + wr * 64 + mi * 16 + g16 * 4;   // even
    const int f0 = cb >> 1;                            // < 512
#pragma unroll
    for (int ni = 0; ni < 4; ++ni) {
      const int t = t0 + wc * 64 + ni * 16 + lr;       // < 1024
      f32x2 v0 = {acc[mi][ni][0], acc[mi][ni][1]};
      f32x2 v1 = {acc[mi][ni][2], acc[mi][ni][3]};
      __builtin_nontemporal_store(
          v0, (f32x2*)(out + ((((size_t)b * FB + f0) * NT + t) << 1)));
      __builtin_nontemporal_store(
          v1, (f32x2*)(out + ((((size_t)b * FB + f0 + 1) * NT + t) << 1)));
    }
  }
}

// ---- edge kernel: Nyquist rows (f=512, all t) and last frame (t=1024, all f) ----
// One wave per output pair (f, t): two 1024-length dots in fp32 from bf16 ws.
__global__ __launch_bounds__(256) void stft_edge(const unsigned short* __restrict__ A,
                                                 const unsigned short* __restrict__ S,
                                                 float* __restrict__ out) {
  const int wv = blockIdx.x * 4 + (threadIdx.x >> 6);
  const int lane = threadIdx.x & 63;
  int b, f, t;
  if (wv < NBATCH * NT) {          // slice a: f = 512, t = 0..1024
    b = wv / NT; t = wv - b * NT; f = FB - 1;
  } else {                          // slice b: t = 1024, f = 0..512
    int u = wv - NBATCH * NT;
    b = u / FB; f = u - b * FB; t = NT - 1;
  }
  const unsigned short* w  = S + (size_t)b * SIGP + (size_t)t * HOP + lane * 16;
  const unsigned short* r0 = A + ((size_t)(2 * f) << 10) + lane * 16;
  const unsigned short* r1 = r0 + 1024;
  short8 wv0 = *(const short8*)w,  wv1 = *(const short8*)(w + 8);
  short8 a0  = *(const short8*)r0, a1  = *(const short8*)(r0 + 8);
  short8 b0  = *(const short8*)r1, b1  = *(const short8*)(r1 + 8);
  float d0 = 0.f, d1 = 0.f;
#pragma unroll
  for (int e = 0; e < 8; ++e) {
    float x0 = bf2f((unsigned short)wv0[e]), x1 = bf2f((unsigned short)wv1[e]);
    d0 += bf2f((unsigned short)a0[e]) * x0 + bf2f((unsigned short)a1[e]) * x1;
    d1 += bf2f((unsigned short)b0[e]) * x0 + bf2f((unsigned short)b1[e]) * x1;
  }
#pragma unroll
  for (int m = 32; m; m >>= 1) {
    d0 += __shfl_xor(d0, m);
    d1 += __shfl_xor(d1, m);
  }
  if (lane == 0)
    *(float2*)(out + ((((size_t)b * FB + f) * NT + t) << 1)) = make_float2(d0, d1);
}

extern "C" void kernel_launch(void* const* d_in, const int* in_sizes, int n_in,
                              void* d_out, int out_size, void* d_ws, size_t ws_size,
                              hipStream_t stream) {
  const float* sig = (const float*)d_in[0];    // (16, 262144) f32
  const float* kern = (const float*)d_in[1];   // (1026, 1024) f32
  float* out = (float*)d_out;                  // (16, 513, 1025, 2) f32

  unsigned short* wsA = (unsigned short*)d_ws;               // 1280*1024 bf16
  unsigned short* wsS = wsA + (size_t)MP2 * NFFT;            // 16*263168 bf16
  // ws use: (1280*1024 + 16*263168)*2 = 11,042,816 bytes

  (void)hipFuncSetAttribute((const void*)stft_mm,
                            hipFuncAttributeMaxDynamicSharedMemorySize, LDS_BYTES);

  prep_A<<<dim3(MP2 * NFFT / 8 / 256), 256, 0, stream>>>(kern, wsA);
  prep_S<<<dim3(NBATCH * SIGP / 8 / 256), 256, 0, stream>>>(sig, wsS);
  stft_mm<<<dim3(4 * 8 * NBATCH), 512, LDS_BYTES, stream>>>(wsA, wsS, out);
  // edge waves: 16*1025 + 16*513 = 24608 = 6152 blocks * 4 waves (exact)
  stft_edge<<<dim3((NBATCH * NT + NBATCH * FB) / 4), 256, 0, stream>>>(wsA, wsS, out);
}